// Round 1
// baseline (236.508 us; speedup 1.0000x reference)
//
#include <hip/hip_runtime.h>
#include <math.h>

#define N_NODES 50000
#define N_EDGES 800000
#define E_TOT   850000     // edges + self-loops
#define HEADS   8
#define HID     32
#define C1      256        // HEADS*HID
#define OUTC    16
#define NEG     0.2f
#define NB1     ((N_NODES + 255) / 256)   // scan blocks = 196 (all co-resident)

__device__ __forceinline__ float lrelu(float v) { return v > 0.0f ? v : NEG * v; }

// ---- fused setup: attention-weight folding + xp pack + CSR count ----
// As1[k][h]=sum_c W1[k,h*32+c]*att_s1[h,c];  As2[k]=sum_j W2[k,j]*att_s2[j]
__global__ __launch_bounds__(256) void k_setup(
    const float* __restrict__ x, const int* __restrict__ ei,
    const float* __restrict__ W1,
    const float* __restrict__ att_s1, const float* __restrict__ att_d1,
    const float* __restrict__ W2,
    const float* __restrict__ att_s2, const float* __restrict__ att_d2,
    float4* __restrict__ xp, int* __restrict__ cnt,
    float* __restrict__ As1, float* __restrict__ Ad1,
    float* __restrict__ As2, float* __restrict__ Ad2)
{
    int t = threadIdx.x;
    int e = blockIdx.x * 256 + t;
    if (blockIdx.x == 0) {
        if (t < 24) {
            int k = t / 8, h = t % 8;
            float as = 0.0f, ad = 0.0f;
            for (int c = 0; c < HID; c++) {
                float w = W1[k * C1 + h * HID + c];
                as = fmaf(w, att_s1[h * HID + c], as);
                ad = fmaf(w, att_d1[h * HID + c], ad);
            }
            As1[k * 8 + h] = as; Ad1[k * 8 + h] = ad;
        }
        float as2 = 0.0f, ad2 = 0.0f;
        for (int j = 0; j < OUTC; j++) {
            float w = W2[t * OUTC + j];
            as2 = fmaf(w, att_s2[j], as2);
            ad2 = fmaf(w, att_d2[j], ad2);
        }
        As2[t] = as2; Ad2[t] = ad2;
    }
    if (e < N_NODES)
        xp[e] = make_float4(x[e * 3], x[e * 3 + 1], x[e * 3 + 2], 1.0f);
    if (e < E_TOT) {
        int d = (e < N_EDGES) ? ei[N_EDGES + e] : (e - N_EDGES);
        atomicAdd(&cnt[d], 1);                 // count only; rank regenerated in k_fill
    }
}

// ---- single-kernel decoupled-lookback exclusive scan over cnt -> off ----
// Also re-zeroes cnt so k_fill can reuse it for rank atomics.
// state[v]: 0 = not ready; bit30|total = aggregate; bit31|inclusive = prefix.
// 196 blocks << 256 CUs => all co-resident, spin-wait is deadlock-free.
__global__ __launch_bounds__(256) void k_scan(
    int* __restrict__ cnt, int* __restrict__ off, unsigned int* __restrict__ state)
{
    __shared__ int s[256];
    __shared__ int sbase;
    int tid = threadIdx.x;
    int v = blockIdx.x;
    int i = v * 256 + tid;
    int val = (i < N_NODES) ? cnt[i] : 0;
    if (i < N_NODES) cnt[i] = 0;
    s[tid] = val;
    __syncthreads();
    for (int o = 1; o < 256; o <<= 1) {
        int t = (tid >= o) ? s[tid - o] : 0;
        __syncthreads();
        s[tid] += t;
        __syncthreads();
    }
    int incl = s[tid];                 // inclusive within block
    int total = s[255];
    if (tid == 0) {
        unsigned pub = (v == 0) ? (0x80000000u | (unsigned)total)
                                : (0x40000000u | (unsigned)total);
        __hip_atomic_store(&state[v], pub, __ATOMIC_RELEASE, __HIP_MEMORY_SCOPE_AGENT);
        sbase = 0;
    }
    if (v > 0 && tid < 64) {
        int run = 0, look = v - 1;
        for (;;) {
            int idx = look - tid;
            unsigned st;
            if (idx >= 0) {
                do {
                    st = __hip_atomic_load(&state[idx], __ATOMIC_RELAXED,
                                           __HIP_MEMORY_SCOPE_AGENT);
                } while (st == 0u);
            } else st = 0x80000000u;   // virtual prefix 0 before block 0
            unsigned long long pm = __ballot((st & 0x80000000u) != 0u);
            int contrib; bool done;
            if (pm) {
                int plane = (int)__ffsll((unsigned long long)pm) - 1; // nearest prefix
                contrib = (tid <= plane) ? (int)(st & 0xFFFFFFu) : 0;
                done = true;
            } else {
                contrib = (int)(st & 0xFFFFFFu);
                done = false;
            }
            for (int o = 32; o > 0; o >>= 1) contrib += __shfl_down(contrib, o);
            run += __shfl(contrib, 0);
            if (done) break;
            look -= 64;
        }
        if (tid == 0) {
            __hip_atomic_store(&state[v], 0x80000000u | (unsigned)(run + total),
                               __ATOMIC_RELEASE, __HIP_MEMORY_SCOPE_AGENT);
            sbase = run;
        }
    }
    __syncthreads();
    if (i < N_NODES) off[i] = sbase + incl - val;   // exclusive prefix
    if (i == 0) off[N_NODES] = E_TOT;
}

// ---- fill CSR: regenerate rank via atomics on the re-zeroed cnt ----
__global__ __launch_bounds__(256) void k_fill(
    const int* __restrict__ ei, int* __restrict__ cnt,
    const int* __restrict__ off, int* __restrict__ csr_src)
{
    int e = blockIdx.x * 256 + threadIdx.x;
    if (e >= E_TOT) return;
    int s, d;
    if (e < N_EDGES) { s = ei[e]; d = ei[N_EDGES + e]; } else { s = d = e - N_EDGES; }
    int r = atomicAdd(&cnt[d], 1);
    csr_src[off[d] + r] = s;
}

// ---- fused layer-1 aggregation + finalize + layer-2 transform ----
// Phase A: 8 lanes per dst (lane = head), 32 dsts/block -> accumulators to LDS.
// Phase B: two halves of 16 nodes x 16 lanes; elu1 and xacc never hit global.
__global__ __launch_bounds__(256) void k_agg1fin(
    const int* __restrict__ off, const int* __restrict__ csr_src,
    const float4* __restrict__ xp,
    const float* __restrict__ As1, const float* __restrict__ Ad1,
    const float* __restrict__ W1, const float* __restrict__ b1,
    const float* __restrict__ W2,
    const float* __restrict__ As2, const float* __restrict__ Ad2,
    float* __restrict__ h2, float* __restrict__ a_s2, float* __restrict__ a_d2)
{
    __shared__ float sW1[3 * C1];        // 3 KB
    __shared__ float sAux[3 * C1];       // b1 | As2 | Ad2, 3 KB
    __shared__ float sW2t[OUTC][260];    // transposed, padded (16.25 KB)
    __shared__ float sElu[16][260];      // padded (16.25 KB)
    __shared__ float4 sXacc[32][8];      // layer-1 accumulators (4 KB)
    int t = threadIdx.x;
    // stage weights early; global-load latency overlaps phase A
    for (int i = t; i < 3 * C1; i += 256) sW1[i] = W1[i];
    sAux[t] = b1[t]; sAux[C1 + t] = As2[t]; sAux[2 * C1 + t] = Ad2[t];
    for (int i = t; i < C1 * OUTC; i += 256) sW2t[i & 15][i >> 4] = W2[i];

    // ---- phase A ----
    int h = t & 7;
    int n8 = t >> 3;
    int dst = blockIdx.x * 32 + n8;
    float a0 = 0.0f, a1 = 0.0f, a2 = 0.0f, a3 = 0.0f;
    if (dst < N_NODES) {
        float s0 = As1[h], s1 = As1[8 + h], s2 = As1[16 + h];
        float d0 = Ad1[h], d1 = Ad1[8 + h], d2 = Ad1[16 + h];
        float4 xd = xp[dst];
        float ad = xd.x * d0 + xd.y * d1 + xd.z * d2;
        int beg = off[dst], end = off[dst + 1];
        int nfull = beg + ((end - beg) & ~7);
        for (int base = beg; base < nfull; base += 8) {
            int sm = csr_src[base + h];
            float4 xv = xp[sm];
            #pragma unroll
            for (int j = 0; j < 8; j++) {
                float vx = __shfl(xv.x, j, 8);
                float vy = __shfl(xv.y, j, 8);
                float vz = __shfl(xv.z, j, 8);
                float as = vx * s0 + vy * s1 + vz * s2;
                float p = __expf(lrelu(as + ad));
                a0 = fmaf(p, vx, a0);
                a1 = fmaf(p, vy, a1);
                a2 = fmaf(p, vz, a2);
                a3 += p;
            }
        }
        if (nfull < end) {                      // tail (< 8 edges)
            int idx = nfull + h;
            int sm = (idx < end) ? csr_src[idx] : 0;
            float4 xv = xp[sm];
            int m = end - nfull;
            for (int j = 0; j < m; j++) {
                float vx = __shfl(xv.x, j, 8);
                float vy = __shfl(xv.y, j, 8);
                float vz = __shfl(xv.z, j, 8);
                float as = vx * s0 + vy * s1 + vz * s2;
                float p = __expf(lrelu(as + ad));
                a0 = fmaf(p, vx, a0);
                a1 = fmaf(p, vy, a1);
                a2 = fmaf(p, vz, a2);
                a3 += p;
            }
        }
    }
    sXacc[n8][h] = make_float4(a0, a1, a2, a3);
    __syncthreads();

    // ---- phase B: finalize + h2 transform, two halves of 16 nodes ----
    int n = t >> 4, l = t & 15;
    #pragma unroll
    for (int half = 0; half < 2; half++) {
        int node = blockIdx.x * 32 + half * 16 + n;
        float as = 0.0f, ad = 0.0f;
        for (int i = 0; i < 16; i++) {
            int c = l + 16 * i;
            float4 xa = sXacc[half * 16 + n][c >> 5];
            float z = (xa.x * sW1[c] + xa.y * sW1[C1 + c] + xa.z * sW1[2 * C1 + c])
                      / (xa.w + 1e-16f) + sAux[c];
            float e = z > 0.0f ? z : expm1f(z);
            sElu[n][c] = e;
            as = fmaf(e, sAux[C1 + c], as);
            ad = fmaf(e, sAux[2 * C1 + c], ad);
        }
        for (int o = 1; o < 16; o <<= 1) {
            as += __shfl_xor(as, o, 64);
            ad += __shfl_xor(ad, o, 64);
        }
        if (l == 0 && node < N_NODES) { a_s2[node] = as; a_d2[node] = ad; }
        __syncthreads();
        const float4* e4 = (const float4*)&sElu[n][0];
        const float4* w4 = (const float4*)&sW2t[l][0];
        float acc = 0.0f;
        #pragma unroll 8
        for (int k = 0; k < 64; k++) {
            float4 a = e4[k], b = w4[k];
            acc = fmaf(a.x, b.x, fmaf(a.y, b.y, fmaf(a.z, b.z, fmaf(a.w, b.w, acc))));
        }
        if (node < N_NODES) h2[node * OUTC + l] = acc;
        if (half == 0) __syncthreads();
    }
}

// ---- layer-2 aggregation: 16 lanes per dst (lane = channel) ----
__global__ __launch_bounds__(256) void k_agg2(
    const int* __restrict__ off, const int* __restrict__ csr_src,
    const float* __restrict__ a_s, const float* __restrict__ a_d,
    const float* __restrict__ h2, const float* __restrict__ bias,
    float* __restrict__ out)
{
    int tid = threadIdx.x;
    int c = tid & 15;
    int dst = blockIdx.x * 16 + (tid >> 4);
    if (dst >= N_NODES) return;
    int beg = off[dst], end = off[dst + 1];
    float ad = a_d[dst];
    float acc = 0.0f, denp = 0.0f;
    int nfull = beg + ((end - beg) & ~15);
    for (int base = beg; base < nfull; base += 16) {
        int sm = csr_src[base + c];
        float p = __expf(lrelu(a_s[sm] + ad));
        denp += p;
        #pragma unroll
        for (int j = 0; j < 16; j++) {
            int s = __shfl(sm, j, 16);
            float pj = __shfl(p, j, 16);
            acc = fmaf(pj, h2[s * OUTC + c], acc);
        }
    }
    if (nfull < end) {                      // tail (< 16 edges)
        int idx = nfull + c;
        int sm = 0; float p = 0.0f;
        if (idx < end) { sm = csr_src[idx]; p = __expf(lrelu(a_s[sm] + ad)); }
        denp += p;
        int m = end - nfull;
        for (int j = 0; j < m; j++) {
            int s = __shfl(sm, j, 16);
            float pj = __shfl(p, j, 16);
            acc = fmaf(pj, h2[s * OUTC + c], acc);
        }
    }
    for (int o = 1; o < 16; o <<= 1) denp += __shfl_xor(denp, o, 16);
    out[dst * OUTC + c] = acc / (denp + 1e-16f) + bias[c];
}

extern "C" void kernel_launch(void* const* d_in, const int* in_sizes, int n_in,
                              void* d_out, int out_size, void* d_ws, size_t ws_size,
                              hipStream_t stream)
{
    (void)in_sizes; (void)n_in; (void)out_size; (void)ws_size;
    const float* x    = (const float*)d_in[0];
    const int*   ei   = (const int*)d_in[1];
    const float* W1   = (const float*)d_in[2];
    const float* as1w = (const float*)d_in[3];
    const float* ad1w = (const float*)d_in[4];
    const float* b1   = (const float*)d_in[5];
    const float* W2   = (const float*)d_in[6];
    const float* as2w = (const float*)d_in[7];
    const float* ad2w = (const float*)d_in[8];
    const float* b2   = (const float*)d_in[9];
    float* out = (float*)d_out;

    const long N = N_NODES;
    char* p = (char*)d_ws;
    auto alloc = [&](size_t elems) {          // 16B-aligned allocations
        void* r = p; p += ((elems + 3) & ~(size_t)3) * 4; return r;
    };

    float4*   xp      = (float4*)alloc(N * 4);
    int*      cnt     = (int*)alloc(N);       // cnt and state contiguous: one memset
    unsigned* state   = (unsigned*)alloc(256);
    int*      off     = (int*)alloc(N + 1);
    int*      csr_src = (int*)alloc(E_TOT);
    float*    As1     = (float*)alloc(32);
    float*    Ad1     = (float*)alloc(32);
    float*    As2     = (float*)alloc(C1);
    float*    Ad2     = (float*)alloc(C1);
    float*    h2v     = (float*)alloc(N * OUTC);
    float*    a_s2    = (float*)alloc(N);
    float*    a_d2    = (float*)alloc(N);

    hipMemsetAsync(cnt, 0, (size_t)(N + 256) * sizeof(int), stream);  // cnt + state

    k_setup<<<(E_TOT + 255) / 256, 256, 0, stream>>>(
        x, ei, W1, as1w, ad1w, W2, as2w, ad2w,
        xp, cnt, As1, Ad1, As2, Ad2);
    k_scan<<<NB1, 256, 0, stream>>>(cnt, off, state);
    k_fill<<<(E_TOT + 255) / 256, 256, 0, stream>>>(ei, cnt, off, csr_src);
    k_agg1fin<<<(int)((N + 31) / 32), 256, 0, stream>>>(
        off, csr_src, xp, As1, Ad1, W1, b1, W2, As2, Ad2, h2v, a_s2, a_d2);
    k_agg2<<<(int)((N + 15) / 16), 256, 0, stream>>>(off, csr_src, a_s2, a_d2, h2v, b2, out);
}

// Round 2
// 223.786 us; speedup vs baseline: 1.0569x; 1.0569x over previous
//
#include <hip/hip_runtime.h>
#include <math.h>

#define N_NODES 50000
#define N_EDGES 800000
#define E_TOT   850000     // edges + self-loops
#define HEADS   8
#define HID     32
#define C1      256        // HEADS*HID
#define OUTC    16
#define NEG     0.2f
#define NB1     ((N_NODES + 255) / 256)   // scan blocks = 196 (all co-resident)

__device__ __forceinline__ float lrelu(float v) { return v > 0.0f ? v : NEG * v; }

// ---- fused setup: attention-weight folding + xp pack + CSR count ----
// As1[k][h]=sum_c W1[k,h*32+c]*att_s1[h,c];  As2[k]=sum_j W2[k,j]*att_s2[j]
__global__ __launch_bounds__(256) void k_setup(
    const float* __restrict__ x, const int* __restrict__ ei,
    const float* __restrict__ W1,
    const float* __restrict__ att_s1, const float* __restrict__ att_d1,
    const float* __restrict__ W2,
    const float* __restrict__ att_s2, const float* __restrict__ att_d2,
    float4* __restrict__ xp, int* __restrict__ cnt,
    float* __restrict__ As1, float* __restrict__ Ad1,
    float* __restrict__ As2, float* __restrict__ Ad2)
{
    int t = threadIdx.x;
    int e = blockIdx.x * 256 + t;
    if (blockIdx.x == 0) {
        if (t < 24) {
            int k = t / 8, h = t % 8;
            float as = 0.0f, ad = 0.0f;
            for (int c = 0; c < HID; c++) {
                float w = W1[k * C1 + h * HID + c];
                as = fmaf(w, att_s1[h * HID + c], as);
                ad = fmaf(w, att_d1[h * HID + c], ad);
            }
            As1[k * 8 + h] = as; Ad1[k * 8 + h] = ad;
        }
        float as2 = 0.0f, ad2 = 0.0f;
        for (int j = 0; j < OUTC; j++) {
            float w = W2[t * OUTC + j];
            as2 = fmaf(w, att_s2[j], as2);
            ad2 = fmaf(w, att_d2[j], ad2);
        }
        As2[t] = as2; Ad2[t] = ad2;
    }
    if (e < N_NODES)
        xp[e] = make_float4(x[e * 3], x[e * 3 + 1], x[e * 3 + 2], 1.0f);
    if (e < E_TOT) {
        int d = (e < N_EDGES) ? ei[N_EDGES + e] : (e - N_EDGES);
        atomicAdd(&cnt[d], 1);                 // count only; rank regenerated in k_fill
    }
}

// ---- single-kernel decoupled-lookback exclusive scan over cnt -> off ----
// Also re-zeroes cnt so k_fill can reuse it for rank atomics.
// state[v]: 0 = not ready; bit30|total = aggregate; bit31|inclusive = prefix.
// 196 blocks << 256 CUs => all co-resident, spin-wait is deadlock-free.
__global__ __launch_bounds__(256) void k_scan(
    int* __restrict__ cnt, int* __restrict__ off, unsigned int* __restrict__ state)
{
    __shared__ int s[256];
    __shared__ int sbase;
    int tid = threadIdx.x;
    int v = blockIdx.x;
    int i = v * 256 + tid;
    int val = (i < N_NODES) ? cnt[i] : 0;
    if (i < N_NODES) cnt[i] = 0;
    s[tid] = val;
    __syncthreads();
    for (int o = 1; o < 256; o <<= 1) {
        int t = (tid >= o) ? s[tid - o] : 0;
        __syncthreads();
        s[tid] += t;
        __syncthreads();
    }
    int incl = s[tid];                 // inclusive within block
    int total = s[255];
    if (tid == 0) {
        unsigned pub = (v == 0) ? (0x80000000u | (unsigned)total)
                                : (0x40000000u | (unsigned)total);
        __hip_atomic_store(&state[v], pub, __ATOMIC_RELEASE, __HIP_MEMORY_SCOPE_AGENT);
        sbase = 0;
    }
    if (v > 0 && tid < 64) {
        int run = 0, look = v - 1;
        for (;;) {
            int idx = look - tid;
            unsigned st;
            if (idx >= 0) {
                do {
                    st = __hip_atomic_load(&state[idx], __ATOMIC_RELAXED,
                                           __HIP_MEMORY_SCOPE_AGENT);
                } while (st == 0u);
            } else st = 0x80000000u;   // virtual prefix 0 before block 0
            unsigned long long pm = __ballot((st & 0x80000000u) != 0u);
            int contrib; bool done;
            if (pm) {
                int plane = (int)__ffsll((unsigned long long)pm) - 1; // nearest prefix
                contrib = (tid <= plane) ? (int)(st & 0xFFFFFFu) : 0;
                done = true;
            } else {
                contrib = (int)(st & 0xFFFFFFu);
                done = false;
            }
            for (int o = 32; o > 0; o >>= 1) contrib += __shfl_down(contrib, o);
            run += __shfl(contrib, 0);
            if (done) break;
            look -= 64;
        }
        if (tid == 0) {
            __hip_atomic_store(&state[v], 0x80000000u | (unsigned)(run + total),
                               __ATOMIC_RELEASE, __HIP_MEMORY_SCOPE_AGENT);
            sbase = run;
        }
    }
    __syncthreads();
    if (i < N_NODES) off[i] = sbase + incl - val;   // exclusive prefix
    if (i == 0) off[N_NODES] = E_TOT;
}

// ---- fill CSR: regenerate rank via atomics on the re-zeroed cnt ----
__global__ __launch_bounds__(256) void k_fill(
    const int* __restrict__ ei, int* __restrict__ cnt,
    const int* __restrict__ off, int* __restrict__ csr_src)
{
    int e = blockIdx.x * 256 + threadIdx.x;
    if (e >= E_TOT) return;
    int s, d;
    if (e < N_EDGES) { s = ei[e]; d = ei[N_EDGES + e]; } else { s = d = e - N_EDGES; }
    int r = atomicAdd(&cnt[d], 1);
    csr_src[off[d] + r] = s;
}

// ---- layer-1 aggregation: 8 lanes per dst (lane = head), shfl-free ----
// All 8 lanes of a group issue the SAME csr/xp addresses (hardware broadcast,
// one transaction per group); 8-edge register batches give 16 loads in flight.
__global__ __launch_bounds__(256) void k_agg1(
    const int* __restrict__ off, const int* __restrict__ csr_src,
    const float4* __restrict__ xp,
    const float* __restrict__ As1, const float* __restrict__ Ad1,
    float4* __restrict__ xaccw)
{
    int tid = threadIdx.x;
    int h = tid & 7;
    int dst = blockIdx.x * 32 + (tid >> 3);
    if (dst >= N_NODES) return;
    float s0 = As1[h], s1 = As1[8 + h], s2 = As1[16 + h];
    float d0 = Ad1[h], d1 = Ad1[8 + h], d2 = Ad1[16 + h];
    float4 xd = xp[dst];
    float ad = xd.x * d0 + xd.y * d1 + xd.z * d2;
    int beg = off[dst], end = off[dst + 1];
    float a0 = 0.0f, a1 = 0.0f, a2 = 0.0f, a3 = 0.0f;
    int k = beg;
    for (; k + 8 <= end; k += 8) {          // full 8-edge batches
        int sm[8]; float4 xv[8];
        #pragma unroll
        for (int j = 0; j < 8; j++) sm[j] = csr_src[k + j];
        #pragma unroll
        for (int j = 0; j < 8; j++) xv[j] = xp[sm[j]];
        #pragma unroll
        for (int j = 0; j < 8; j++) {
            float as = xv[j].x * s0 + xv[j].y * s1 + xv[j].z * s2;
            float p = __expf(lrelu(as + ad));
            a0 = fmaf(p, xv[j].x, a0);
            a1 = fmaf(p, xv[j].y, a1);
            a2 = fmaf(p, xv[j].z, a2);
            a3 += p;
        }
    }
    if (k < end) {                          // masked tail batch (keeps ILP)
        int m = end - k;
        int sm[8]; float4 xv[8];
        #pragma unroll
        for (int j = 0; j < 8; j++) { int idx = k + j; sm[j] = csr_src[idx < end ? idx : k]; }
        #pragma unroll
        for (int j = 0; j < 8; j++) xv[j] = xp[sm[j]];
        #pragma unroll
        for (int j = 0; j < 8; j++) {
            float as = xv[j].x * s0 + xv[j].y * s1 + xv[j].z * s2;
            float p = __expf(lrelu(as + ad));
            p = (j < m) ? p : 0.0f;
            a0 = fmaf(p, xv[j].x, a0);
            a1 = fmaf(p, xv[j].y, a1);
            a2 = fmaf(p, xv[j].z, a2);
            a3 += p;
        }
    }
    xaccw[dst * 8 + h] = make_float4(a0, a1, a2, a3);
}

// ---- fused finalize layer1 + layer2 transform (elu1 never hits global) ----
// block = 256 threads = 16 nodes x 16 lanes
__global__ __launch_bounds__(256) void k_fin1h2(
    const float4* __restrict__ xaccw, const float* __restrict__ W1,
    const float* __restrict__ b1, const float* __restrict__ W2,
    const float* __restrict__ As2, const float* __restrict__ Ad2,
    float* __restrict__ h2, float* __restrict__ a_s2, float* __restrict__ a_d2)
{
    __shared__ float sW1[3 * C1];        // 3 KB
    __shared__ float sAux[3 * C1];       // b1 | As2 | Ad2, 3 KB
    __shared__ float sW2t[OUTC][260];    // transposed, padded
    __shared__ float sElu[16][260];      // padded
    int t = threadIdx.x;
    for (int i = t; i < 3 * C1; i += 256) sW1[i] = W1[i];
    sAux[t] = b1[t]; sAux[C1 + t] = As2[t]; sAux[2 * C1 + t] = Ad2[t];
    for (int i = t; i < C1 * OUTC; i += 256) {
        int k = i >> 4, j = i & 15;
        sW2t[j][k] = W2[i];
    }
    __syncthreads();
    int n = t >> 4, l = t & 15;
    int node = blockIdx.x * 16 + n;
    float as = 0.0f, ad = 0.0f;
    for (int i = 0; i < 16; i++) {
        int c = l + 16 * i;
        int h = c >> 5;
        float4 xa = xaccw[node * 8 + h];
        float z = (xa.x * sW1[c] + xa.y * sW1[C1 + c] + xa.z * sW1[2 * C1 + c])
                  / (xa.w + 1e-16f) + sAux[c];
        float e = z > 0.0f ? z : expm1f(z);
        sElu[n][c] = e;
        as = fmaf(e, sAux[C1 + c], as);
        ad = fmaf(e, sAux[2 * C1 + c], ad);
    }
    for (int o = 1; o < 16; o <<= 1) {
        as += __shfl_xor(as, o, 64);
        ad += __shfl_xor(ad, o, 64);
    }
    if (l == 0) { a_s2[node] = as; a_d2[node] = ad; }
    __syncthreads();
    const float4* e4 = (const float4*)&sElu[n][0];
    const float4* w4 = (const float4*)&sW2t[l][0];
    float acc = 0.0f;
    #pragma unroll 8
    for (int k = 0; k < 64; k++) {
        float4 a = e4[k], b = w4[k];
        acc = fmaf(a.x, b.x, fmaf(a.y, b.y, fmaf(a.z, b.z, fmaf(a.w, b.w, acc))));
    }
    h2[node * OUTC + l] = acc;
}

// ---- layer-2 aggregation: 16 lanes per dst (lane = channel), shfl-free ----
// csr/a_s loads are group-broadcast; h2 gather is one 64B line per edge.
// denp is computed identically in every lane -> no cross-lane reduce needed.
__global__ __launch_bounds__(256) void k_agg2(
    const int* __restrict__ off, const int* __restrict__ csr_src,
    const float* __restrict__ a_s, const float* __restrict__ a_d,
    const float* __restrict__ h2, const float* __restrict__ bias,
    float* __restrict__ out)
{
    int tid = threadIdx.x;
    int c = tid & 15;
    int dst = blockIdx.x * 16 + (tid >> 4);
    if (dst >= N_NODES) return;
    int beg = off[dst], end = off[dst + 1];
    float ad = a_d[dst];
    float acc = 0.0f, denp = 0.0f;
    int k = beg;
    for (; k + 8 <= end; k += 8) {          // full 8-edge batches
        int sm[8]; float p[8];
        #pragma unroll
        for (int j = 0; j < 8; j++) sm[j] = csr_src[k + j];
        #pragma unroll
        for (int j = 0; j < 8; j++) p[j] = __expf(lrelu(a_s[sm[j]] + ad));
        #pragma unroll
        for (int j = 0; j < 8; j++) {
            denp += p[j];
            acc = fmaf(p[j], h2[sm[j] * OUTC + c], acc);
        }
    }
    if (k < end) {                          // masked tail batch
        int m = end - k;
        int sm[8]; float p[8];
        #pragma unroll
        for (int j = 0; j < 8; j++) { int idx = k + j; sm[j] = csr_src[idx < end ? idx : k]; }
        #pragma unroll
        for (int j = 0; j < 8; j++) {
            float pj = __expf(lrelu(a_s[sm[j]] + ad));
            p[j] = (j < m) ? pj : 0.0f;
        }
        #pragma unroll
        for (int j = 0; j < 8; j++) {
            denp += p[j];
            acc = fmaf(p[j], h2[sm[j] * OUTC + c], acc);
        }
    }
    out[dst * OUTC + c] = acc / (denp + 1e-16f) + bias[c];
}

extern "C" void kernel_launch(void* const* d_in, const int* in_sizes, int n_in,
                              void* d_out, int out_size, void* d_ws, size_t ws_size,
                              hipStream_t stream)
{
    (void)in_sizes; (void)n_in; (void)out_size; (void)ws_size;
    const float* x    = (const float*)d_in[0];
    const int*   ei   = (const int*)d_in[1];
    const float* W1   = (const float*)d_in[2];
    const float* as1w = (const float*)d_in[3];
    const float* ad1w = (const float*)d_in[4];
    const float* b1   = (const float*)d_in[5];
    const float* W2   = (const float*)d_in[6];
    const float* as2w = (const float*)d_in[7];
    const float* ad2w = (const float*)d_in[8];
    const float* b2   = (const float*)d_in[9];
    float* out = (float*)d_out;

    const long N = N_NODES;
    char* p = (char*)d_ws;
    auto alloc = [&](size_t elems) {          // 16B-aligned allocations
        void* r = p; p += ((elems + 3) & ~(size_t)3) * 4; return r;
    };

    float4*   xp      = (float4*)alloc(N * 4);
    float4*   xaccw   = (float4*)alloc(N * HEADS * 4);
    int*      cnt     = (int*)alloc(N);       // cnt and state contiguous: one memset
    unsigned* state   = (unsigned*)alloc(256);
    int*      off     = (int*)alloc(N + 1);
    int*      csr_src = (int*)alloc(E_TOT);
    float*    As1     = (float*)alloc(32);
    float*    Ad1     = (float*)alloc(32);
    float*    As2     = (float*)alloc(C1);
    float*    Ad2     = (float*)alloc(C1);
    float*    h2v     = (float*)alloc(N * OUTC);
    float*    a_s2    = (float*)alloc(N);
    float*    a_d2    = (float*)alloc(N);

    hipMemsetAsync(cnt, 0, (size_t)(N + 256) * sizeof(int), stream);  // cnt + state

    k_setup<<<(E_TOT + 255) / 256, 256, 0, stream>>>(
        x, ei, W1, as1w, ad1w, W2, as2w, ad2w,
        xp, cnt, As1, Ad1, As2, Ad2);
    k_scan<<<NB1, 256, 0, stream>>>(cnt, off, state);
    k_fill<<<(E_TOT + 255) / 256, 256, 0, stream>>>(ei, cnt, off, csr_src);
    k_agg1<<<(int)((N + 31) / 32), 256, 0, stream>>>(off, csr_src, xp, As1, Ad1, xaccw);
    k_fin1h2<<<(int)(N / 16), 256, 0, stream>>>(xaccw, W1, b1, W2, As2, Ad2, h2v, a_s2, a_d2);
    k_agg2<<<(int)((N + 15) / 16), 256, 0, stream>>>(off, csr_src, a_s2, a_d2, h2v, b2, out);
}

// Round 3
// 162.837 us; speedup vs baseline: 1.4524x; 1.3743x over previous
//
#include <hip/hip_runtime.h>
#include <math.h>

#define N_NODES 50000
#define N_EDGES 800000
#define E_TOT   850000     // edges + self-loops
#define HEADS   8
#define HID     32
#define C1      256        // HEADS*HID
#define OUTC    16
#define NEG     0.2f
#define NBKT    196        // ceil(N_NODES/256) coarse dst-buckets
#define BCAP    6144       // per-bucket staging capacity (mean 4337, +27 sigma)
#define EPB     4096       // edges per k_setup block
#define NSB     ((E_TOT + EPB - 1) / EPB)   // 208 setup blocks

__device__ __forceinline__ float lrelu(float v) { return v > 0.0f ? v : NEG * v; }

// ---- fused setup: weight folding + xp pack + LDS-binned edge staging ----
// Edges packed as (d<<16)|s (both < 65536) and scattered into 196 coarse
// buckets in ~16-element runs per (block,bucket): single-XCD line writes,
// no cross-XCD partial-line amplification.
__global__ __launch_bounds__(256) void k_setup(
    const float* __restrict__ x, const int* __restrict__ ei,
    const float* __restrict__ W1,
    const float* __restrict__ att_s1, const float* __restrict__ att_d1,
    const float* __restrict__ W2,
    const float* __restrict__ att_s2, const float* __restrict__ att_d2,
    float4* __restrict__ xp,
    unsigned* __restrict__ bucket_cnt, unsigned* __restrict__ ebuf,
    float* __restrict__ As1, float* __restrict__ Ad1,
    float* __restrict__ As2, float* __restrict__ Ad2)
{
    __shared__ unsigned hist[256];
    __shared__ unsigned gpos[256];
    int t = threadIdx.x;
    int blk = blockIdx.x;
    if (blk == 0) {
        if (t < 24) {
            int k = t / 8, h = t % 8;
            float as = 0.0f, ad = 0.0f;
            for (int c = 0; c < HID; c++) {
                float w = W1[k * C1 + h * HID + c];
                as = fmaf(w, att_s1[h * HID + c], as);
                ad = fmaf(w, att_d1[h * HID + c], ad);
            }
            As1[k * 8 + h] = as; Ad1[k * 8 + h] = ad;
        }
        float as2 = 0.0f, ad2 = 0.0f;
        for (int j = 0; j < OUTC; j++) {
            float w = W2[t * OUTC + j];
            as2 = fmaf(w, att_s2[j], as2);
            ad2 = fmaf(w, att_d2[j], ad2);
        }
        As2[t] = as2; Ad2[t] = ad2;
    }
    int nid = blk * 256 + t;
    if (nid < N_NODES)
        xp[nid] = make_float4(x[nid * 3], x[nid * 3 + 1], x[nid * 3 + 2], 1.0f);

    hist[t] = 0;
    __syncthreads();
    unsigned pk[16]; unsigned short rk[16]; unsigned char bk[16];
    int e0 = blk * EPB;
    #pragma unroll
    for (int j = 0; j < 16; j++) {
        int e = e0 + j * 256 + t;
        if (e < E_TOT) {
            int s, d;
            if (e < N_EDGES) { s = ei[e]; d = ei[N_EDGES + e]; }
            else             { s = d = e - N_EDGES; }
            pk[j] = ((unsigned)d << 16) | (unsigned)s;
            int b = d >> 8;
            bk[j] = (unsigned char)b;
            rk[j] = (unsigned short)atomicAdd(&hist[b], 1u);
        } else { pk[j] = 0u; bk[j] = 0; rk[j] = 0; }
    }
    __syncthreads();
    unsigned c = hist[t];
    gpos[t] = c ? atomicAdd(&bucket_cnt[t], c) : 0u;
    __syncthreads();
    #pragma unroll
    for (int j = 0; j < 16; j++) {
        int e = e0 + j * 256 + t;
        if (e < E_TOT) {
            unsigned b = bk[j];
            ebuf[b * BCAP + gpos[b] + rk[j]] = pk[j];
        }
    }
}

// ---- bucket -> CSR: one block per bucket (256 consecutive dst ids) ----
// Per-dst rank via LDS atomics; writes off[] for its dst range and a
// contiguous ~cnt_b*2B csr region (ushort src ids): full-line writebacks.
__global__ __launch_bounds__(256) void k_csr(
    const unsigned* __restrict__ bucket_cnt, const unsigned* __restrict__ ebuf,
    int* __restrict__ off, unsigned short* __restrict__ csr)
{
    __shared__ unsigned s[256];
    __shared__ unsigned dcnt[256];
    __shared__ unsigned dscan[256];
    int t = threadIdx.x, b = blockIdx.x;
    unsigned cntb = bucket_cnt[b];
    s[t] = (t < NBKT) ? bucket_cnt[t] : 0u;
    dcnt[t] = 0u;
    __syncthreads();
    for (int o = 1; o < 256; o <<= 1) {            // inclusive scan of bucket sizes
        unsigned v = (t >= o) ? s[t - o] : 0u;
        __syncthreads();
        s[t] += v;
        __syncthreads();
    }
    unsigned base = (b == 0) ? 0u : s[b - 1];
    unsigned ev[24]; unsigned short rk[24];
    #pragma unroll
    for (int j = 0; j < 24; j++) {                 // 24*256 = 6144 = BCAP
        int i = j * 256 + t;
        if (i < (int)cntb) {
            unsigned v = ebuf[b * BCAP + i];
            ev[j] = v;
            rk[j] = (unsigned short)atomicAdd(&dcnt[(v >> 16) & 255u], 1u);
        } else { ev[j] = 0u; rk[j] = 0; }
    }
    __syncthreads();
    dscan[t] = dcnt[t];
    __syncthreads();
    for (int o = 1; o < 256; o <<= 1) {            // inclusive scan of per-dst counts
        unsigned v = (t >= o) ? dscan[t - o] : 0u;
        __syncthreads();
        dscan[t] += v;
        __syncthreads();
    }
    int d = b * 256 + t;
    if (d <= N_NODES) off[d] = (int)(base + dscan[t] - dcnt[t]);  // exclusive
    #pragma unroll
    for (int j = 0; j < 24; j++) {
        int i = j * 256 + t;
        if (i < (int)cntb) {
            unsigned d8 = (ev[j] >> 16) & 255u;
            unsigned pos = base + (dscan[d8] - dcnt[d8]) + rk[j];
            csr[pos] = (unsigned short)(ev[j] & 0xFFFFu);
        }
    }
}

// ---- layer-1 aggregation: 8 lanes per dst (lane = head), shfl-free ----
// All 8 lanes of a group issue the SAME csr/xp addresses (hardware broadcast);
// 8-edge register batches keep 16 loads in flight.
__global__ __launch_bounds__(256) void k_agg1(
    const int* __restrict__ off, const unsigned short* __restrict__ csr,
    const float4* __restrict__ xp,
    const float* __restrict__ As1, const float* __restrict__ Ad1,
    float4* __restrict__ xaccw)
{
    int tid = threadIdx.x;
    int h = tid & 7;
    int dst = blockIdx.x * 32 + (tid >> 3);
    if (dst >= N_NODES) return;
    float s0 = As1[h], s1 = As1[8 + h], s2 = As1[16 + h];
    float d0 = Ad1[h], d1 = Ad1[8 + h], d2 = Ad1[16 + h];
    float4 xd = xp[dst];
    float ad = xd.x * d0 + xd.y * d1 + xd.z * d2;
    int beg = off[dst], end = off[dst + 1];
    float a0 = 0.0f, a1 = 0.0f, a2 = 0.0f, a3 = 0.0f;
    int k = beg;
    for (; k + 8 <= end; k += 8) {          // full 8-edge batches
        int sm[8]; float4 xv[8];
        #pragma unroll
        for (int j = 0; j < 8; j++) sm[j] = csr[k + j];
        #pragma unroll
        for (int j = 0; j < 8; j++) xv[j] = xp[sm[j]];
        #pragma unroll
        for (int j = 0; j < 8; j++) {
            float as = xv[j].x * s0 + xv[j].y * s1 + xv[j].z * s2;
            float p = __expf(lrelu(as + ad));
            a0 = fmaf(p, xv[j].x, a0);
            a1 = fmaf(p, xv[j].y, a1);
            a2 = fmaf(p, xv[j].z, a2);
            a3 += p;
        }
    }
    if (k < end) {                          // masked tail batch (keeps ILP)
        int m = end - k;
        int sm[8]; float4 xv[8];
        #pragma unroll
        for (int j = 0; j < 8; j++) { int idx = k + j; sm[j] = csr[idx < end ? idx : k]; }
        #pragma unroll
        for (int j = 0; j < 8; j++) xv[j] = xp[sm[j]];
        #pragma unroll
        for (int j = 0; j < 8; j++) {
            float as = xv[j].x * s0 + xv[j].y * s1 + xv[j].z * s2;
            float p = __expf(lrelu(as + ad));
            p = (j < m) ? p : 0.0f;
            a0 = fmaf(p, xv[j].x, a0);
            a1 = fmaf(p, xv[j].y, a1);
            a2 = fmaf(p, xv[j].z, a2);
            a3 += p;
        }
    }
    xaccw[dst * 8 + h] = make_float4(a0, a1, a2, a3);
}

// ---- fused finalize layer1 + layer2 transform (elu1 never hits global) ----
// block = 256 threads = 16 nodes x 16 lanes
__global__ __launch_bounds__(256) void k_fin1h2(
    const float4* __restrict__ xaccw, const float* __restrict__ W1,
    const float* __restrict__ b1, const float* __restrict__ W2,
    const float* __restrict__ As2, const float* __restrict__ Ad2,
    float* __restrict__ h2, float* __restrict__ a_s2, float* __restrict__ a_d2)
{
    __shared__ float sW1[3 * C1];        // 3 KB
    __shared__ float sAux[3 * C1];       // b1 | As2 | Ad2, 3 KB
    __shared__ float sW2t[OUTC][260];    // transposed, padded
    __shared__ float sElu[16][260];      // padded
    int t = threadIdx.x;
    for (int i = t; i < 3 * C1; i += 256) sW1[i] = W1[i];
    sAux[t] = b1[t]; sAux[C1 + t] = As2[t]; sAux[2 * C1 + t] = Ad2[t];
    for (int i = t; i < C1 * OUTC; i += 256) {
        int k = i >> 4, j = i & 15;
        sW2t[j][k] = W2[i];
    }
    __syncthreads();
    int n = t >> 4, l = t & 15;
    int node = blockIdx.x * 16 + n;
    float as = 0.0f, ad = 0.0f;
    for (int i = 0; i < 16; i++) {
        int c = l + 16 * i;
        int h = c >> 5;
        float4 xa = xaccw[node * 8 + h];
        float z = (xa.x * sW1[c] + xa.y * sW1[C1 + c] + xa.z * sW1[2 * C1 + c])
                  / (xa.w + 1e-16f) + sAux[c];
        float e = z > 0.0f ? z : expm1f(z);
        sElu[n][c] = e;
        as = fmaf(e, sAux[C1 + c], as);
        ad = fmaf(e, sAux[2 * C1 + c], ad);
    }
    for (int o = 1; o < 16; o <<= 1) {
        as += __shfl_xor(as, o, 64);
        ad += __shfl_xor(ad, o, 64);
    }
    if (l == 0) { a_s2[node] = as; a_d2[node] = ad; }
    __syncthreads();
    const float4* e4 = (const float4*)&sElu[n][0];
    const float4* w4 = (const float4*)&sW2t[l][0];
    float acc = 0.0f;
    #pragma unroll 8
    for (int k = 0; k < 64; k++) {
        float4 a = e4[k], b = w4[k];
        acc = fmaf(a.x, b.x, fmaf(a.y, b.y, fmaf(a.z, b.z, fmaf(a.w, b.w, acc))));
    }
    h2[node * OUTC + l] = acc;
}

// ---- layer-2 aggregation: 16 lanes per dst (lane = channel), shfl-free ----
// csr/a_s loads are group-broadcast; h2 gather is one 64B line per edge.
// denp is computed identically in every lane -> no cross-lane reduce needed.
__global__ __launch_bounds__(256) void k_agg2(
    const int* __restrict__ off, const unsigned short* __restrict__ csr,
    const float* __restrict__ a_s, const float* __restrict__ a_d,
    const float* __restrict__ h2, const float* __restrict__ bias,
    float* __restrict__ out)
{
    int tid = threadIdx.x;
    int c = tid & 15;
    int dst = blockIdx.x * 16 + (tid >> 4);
    if (dst >= N_NODES) return;
    int beg = off[dst], end = off[dst + 1];
    float ad = a_d[dst];
    float acc = 0.0f, denp = 0.0f;
    int k = beg;
    for (; k + 8 <= end; k += 8) {          // full 8-edge batches
        int sm[8]; float p[8];
        #pragma unroll
        for (int j = 0; j < 8; j++) sm[j] = csr[k + j];
        #pragma unroll
        for (int j = 0; j < 8; j++) p[j] = __expf(lrelu(a_s[sm[j]] + ad));
        #pragma unroll
        for (int j = 0; j < 8; j++) {
            denp += p[j];
            acc = fmaf(p[j], h2[sm[j] * OUTC + c], acc);
        }
    }
    if (k < end) {                          // masked tail batch
        int m = end - k;
        int sm[8]; float p[8];
        #pragma unroll
        for (int j = 0; j < 8; j++) { int idx = k + j; sm[j] = csr[idx < end ? idx : k]; }
        #pragma unroll
        for (int j = 0; j < 8; j++) {
            float pj = __expf(lrelu(a_s[sm[j]] + ad));
            p[j] = (j < m) ? pj : 0.0f;
        }
        #pragma unroll
        for (int j = 0; j < 8; j++) {
            denp += p[j];
            acc = fmaf(p[j], h2[sm[j] * OUTC + c], acc);
        }
    }
    out[dst * OUTC + c] = acc / (denp + 1e-16f) + bias[c];
}

extern "C" void kernel_launch(void* const* d_in, const int* in_sizes, int n_in,
                              void* d_out, int out_size, void* d_ws, size_t ws_size,
                              hipStream_t stream)
{
    (void)in_sizes; (void)n_in; (void)out_size; (void)ws_size;
    const float* x    = (const float*)d_in[0];
    const int*   ei   = (const int*)d_in[1];
    const float* W1   = (const float*)d_in[2];
    const float* as1w = (const float*)d_in[3];
    const float* ad1w = (const float*)d_in[4];
    const float* b1   = (const float*)d_in[5];
    const float* W2   = (const float*)d_in[6];
    const float* as2w = (const float*)d_in[7];
    const float* ad2w = (const float*)d_in[8];
    const float* b2   = (const float*)d_in[9];
    float* out = (float*)d_out;

    const long N = N_NODES;
    char* p = (char*)d_ws;
    auto alloc = [&](size_t elems) {          // 16B-aligned 4B-elem allocations
        void* r = p; p += ((elems + 3) & ~(size_t)3) * 4; return r;
    };

    float4*         xp     = (float4*)alloc(N * 4);
    float4*         xaccw  = (float4*)alloc(N * HEADS * 4);
    unsigned*       bcnt   = (unsigned*)alloc(256);
    unsigned*       ebuf   = (unsigned*)alloc((size_t)NBKT * BCAP);
    int*            off    = (int*)alloc(N + 1);
    unsigned short* csr    = (unsigned short*)alloc((E_TOT + 1) / 2);
    float*          As1    = (float*)alloc(32);
    float*          Ad1    = (float*)alloc(32);
    float*          As2    = (float*)alloc(C1);
    float*          Ad2    = (float*)alloc(C1);
    float*          h2v    = (float*)alloc(N * OUTC);
    float*          a_s2   = (float*)alloc(N);
    float*          a_d2   = (float*)alloc(N);

    hipMemsetAsync(bcnt, 0, 256 * sizeof(unsigned), stream);   // 1 KB only

    k_setup<<<NSB, 256, 0, stream>>>(
        x, ei, W1, as1w, ad1w, W2, as2w, ad2w,
        xp, bcnt, ebuf, As1, Ad1, As2, Ad2);
    k_csr<<<NBKT, 256, 0, stream>>>(bcnt, ebuf, off, csr);
    k_agg1<<<(int)((N + 31) / 32), 256, 0, stream>>>(off, csr, xp, As1, Ad1, xaccw);
    k_fin1h2<<<(int)(N / 16), 256, 0, stream>>>(xaccw, W1, b1, W2, As2, Ad2, h2v, a_s2, a_d2);
    k_agg2<<<(int)((N + 15) / 16), 256, 0, stream>>>(off, csr, a_s2, a_d2, h2v, b2, out);
}